// Round 11
// baseline (1724.722 us; speedup 1.0000x reference)
//
#include <hip/hip_runtime.h>
#include <cmath>

// Problem constants (from reference)
constexpr int NN = 50000;      // nodes
constexpr int NE = 1600000;    // edges
constexpr int H  = 64;         // hidden
constexpr int NL = 5;          // layers
constexpr int NG = 4;          // graphs
constexpr int EIN = 2 * H + 5; // 133
constexpr int NIN = 2 * H;     // 128

typedef short bf16x8 __attribute__((ext_vector_type(8)));
typedef float f32x4  __attribute__((ext_vector_type(4)));

__device__ __forceinline__ float silu_f(float x) {
    return x / (1.0f + __expf(-x));
}

// round-to-nearest-even fp32 -> bf16 bits
__device__ __forceinline__ unsigned int f2bf(float f) {
    unsigned int u = __float_as_uint(f);
    u += 0x7fffu + ((u >> 16) & 1u);
    return u >> 16;
}
__device__ __forceinline__ unsigned int pack_bf16x2(float x, float y) {
    return f2bf(x) | (f2bf(y) << 16);
}

// DPP lane-shift within 16-lane rows (VALU pipe, not ds_bpermute).
// row_shr:N = 0x110|N (lane i <- lane i-N within row); row_shl:1 = 0x101.
// bound_ctrl=false: out-of-row lanes keep `old`.
template <int CTRL>
__device__ __forceinline__ int dpp_i(int old, int v) {
    return __builtin_amdgcn_update_dpp(old, v, CTRL, 0xF, 0xF, false);
}

// ---------------------------------------------------------------------------
// Counting sort of edges by dst
// ---------------------------------------------------------------------------
__global__ __launch_bounds__(256) void degree_kernel(
    const int* __restrict__ ei, int* __restrict__ deg)
{
    int e = blockIdx.x * 256 + threadIdx.x;
    if (e < NE) atomicAdd(&deg[ei[NE + e]], 1);
}

// Hierarchical exclusive scan: 49 parallel block scans -> 1-wave scan of
// block sums -> add block bases.
__global__ __launch_bounds__(1024) void scan1_kernel(
    const int* __restrict__ deg, int* __restrict__ off, int* __restrict__ bsum)
{
    __shared__ int sh[1024];
    const int tid = threadIdx.x;
    int i = blockIdx.x * 1024 + tid;
    int v = (i < NN) ? deg[i] : 0;
    sh[tid] = v;
    __syncthreads();
    for (int d = 1; d < 1024; d <<= 1) {
        int t = (tid >= d) ? sh[tid - d] : 0;
        __syncthreads();
        sh[tid] += t;
        __syncthreads();
    }
    if (i < NN) off[i] = sh[tid] - v;          // block-local exclusive
    if (tid == 1023) bsum[blockIdx.x] = sh[1023];
}

__global__ __launch_bounds__(64) void scan2_kernel(
    const int* __restrict__ bsum, int* __restrict__ bbase, int nb)
{
    int lane = threadIdx.x;
    int v = (lane < nb) ? bsum[lane] : 0;
    int orig = v;
    for (int d = 1; d < 64; d <<= 1) {
        int t = __shfl_up(v, d);
        if (lane >= d) v += t;
    }
    bbase[lane] = v - orig;                    // exclusive
}

__global__ __launch_bounds__(1024) void scan3_kernel(
    int* __restrict__ off, const int* __restrict__ bbase,
    int* __restrict__ cursor)
{
    int i = blockIdx.x * 1024 + threadIdx.x;
    if (i < NN) {
        int o = off[i] + bbase[blockIdx.x];
        off[i] = o;
        cursor[i] = o;
        if (i == NN - 1) off[NN] = NE;
    }
}

__global__ __launch_bounds__(256) void scatter_kernel(
    const int* __restrict__ ei, int* __restrict__ cursor,
    int* __restrict__ sidx, int* __restrict__ sdst, int* __restrict__ ssrc)
{
    int e = blockIdx.x * 256 + threadIdx.x;
    if (e < NE) {
        int d = ei[NE + e];
        int p = atomicAdd(&cursor[d], 1);
        sidx[p] = e;
        sdst[p] = d;
        ssrc[p] = ei[e];
    }
}

// ---------------------------------------------------------------------------
// Pre-pack edge_attr into sorted-edge order, bf16, 16B/edge (5 vals + 3 zero).
// This IS the MFMA B-fragment for (ks=4, quad=0): k=128..135 = {ea0..ea4,0,0,0}.
// ---------------------------------------------------------------------------
__global__ __launch_bounds__(256) void ea_pack_kernel(
    const float* __restrict__ ea, const int* __restrict__ sidx,
    uint4* __restrict__ ea_pk)
{
    int p = blockIdx.x * 256 + threadIdx.x;
    if (p < NE) {
        const float* s = ea + (size_t)sidx[p] * 5;
        uint4 v;
        v.x = pack_bf16x2(s[0], s[1]);
        v.y = pack_bf16x2(s[2], s[3]);
        v.z = pack_bf16x2(s[4], 0.0f);
        v.w = 0u;
        ea_pk[p] = v;
    }
}

// ---------------------------------------------------------------------------
// Pre-pack MLP weights into MFMA A-fragment order (bf16).
// elem(ks, mt, lane, j) = W[k = ks*32 + (lane>>4)*8 + j][ch = mt*16 + (lane&15)]
// ---------------------------------------------------------------------------
__global__ __launch_bounds__(256) void pack_weights_kernel(
    const float* __restrict__ eW1, const float* __restrict__ eW2,
    const float* __restrict__ nW1, const float* __restrict__ nW2,
    const float* __restrict__ dlW1, const float* __restrict__ dlW2,
    short* __restrict__ eW1pk, short* __restrict__ eW2pk,
    short* __restrict__ nW1pk, short* __restrict__ nW2pk,
    short* __restrict__ dlW1pk, short* __restrict__ dlW2pk)
{
    int l = blockIdx.y;
    int t = blockIdx.x * 256 + threadIdx.x;
    if (t < 10240) {
        int j = t & 7, lane = (t >> 3) & 63, mt = (t >> 9) & 3, ks = t >> 11;
        int k  = ks * 32 + (lane >> 4) * 8 + j;
        int ch = mt * 16 + (lane & 15);
        float v = (k < EIN) ? eW1[(size_t)l * EIN * H + k * H + ch] : 0.0f;
        eW1pk[(size_t)l * 10240 + t] = (short)f2bf(v);
    } else if (t < 14336) {
        int t2 = t - 10240;
        int j = t2 & 7, lane = (t2 >> 3) & 63, mt = (t2 >> 9) & 3, ks = t2 >> 11;
        int k = ks * 32 + (lane >> 4) * 8 + j;
        int ch = mt * 16 + (lane & 15);
        eW2pk[(size_t)l * 4096 + t2] = (short)f2bf(eW2[(size_t)l * H * H + k * H + ch]);
    } else if (t < 22528) {
        int t3 = t - 14336;
        int j = t3 & 7, lane = (t3 >> 3) & 63, mt = (t3 >> 9) & 3, ks = t3 >> 11;
        int k = ks * 32 + (lane >> 4) * 8 + j;
        int ch = mt * 16 + (lane & 15);
        nW1pk[(size_t)l * 8192 + t3] = (short)f2bf(nW1[(size_t)l * NIN * H + k * H + ch]);
    } else if (t < 26624) {
        int t4 = t - 22528;
        int j = t4 & 7, lane = (t4 >> 3) & 63, mt = (t4 >> 9) & 3, ks = t4 >> 11;
        int k = ks * 32 + (lane >> 4) * 8 + j;
        int ch = mt * 16 + (lane & 15);
        nW2pk[(size_t)l * 4096 + t4] = (short)f2bf(nW2[(size_t)l * H * H + k * H + ch]);
    } else if (t < 30720) {
        if (l == 0) {
            int t5 = t - 26624;
            int j = t5 & 7, lane = (t5 >> 3) & 63, mt = (t5 >> 9) & 3, ks = t5 >> 11;
            int k = ks * 32 + (lane >> 4) * 8 + j;
            int ch = mt * 16 + (lane & 15);
            dlW1pk[t5] = (short)f2bf(dlW1[k * H + ch]);
        }
    } else if (t < 31744) {
        if (l == 0) {
            int t6 = t - 30720;
            int j = t6 & 7, lane = (t6 >> 3) & 63, ks = t6 >> 9;
            int k = ks * 32 + (lane >> 4) * 8 + j;
            int m = lane & 15;
            float v = (m < 6) ? dlW2[k * 6 + m] : 0.0f;
            dlW2pk[t6] = (short)f2bf(v);
        }
    }
}

// ---------------------------------------------------------------------------
// Encoder: h = LN(silu([x, gv[batch]] @ W1 + b1) @ W2 + b2); writes h (fp32)
// and h2 (bf16 mirror used by MFMA staging).
// ---------------------------------------------------------------------------
__global__ __launch_bounds__(256) void encoder_kernel(
    const float* __restrict__ x, const int* __restrict__ batch,
    const float* __restrict__ case_p, const float* __restrict__ bc_p,
    const float* __restrict__ W1, const float* __restrict__ b1,
    const float* __restrict__ W2, const float* __restrict__ b2,
    const float* __restrict__ g, const float* __restrict__ be,
    float* __restrict__ h, unsigned int* __restrict__ h2)
{
    __shared__ float in_sh[64 * 17];
    __shared__ float m1_sh[64 * 65];
    __shared__ float red_sh[2 * 4 * 64];
    const int lane = threadIdx.x & 63;
    const int w    = threadIdx.x >> 6;
    const int wb   = __builtin_amdgcn_readfirstlane(w * 16);
    const int n0   = blockIdx.x * 64;

    for (int i = 0; i < 16; ++i) {
        int slot = w * 16 + i;
        int n = n0 + slot;
        if (n < NN && lane < 16) {
            float v;
            if (lane < 8) v = x[n * 8 + lane];
            else {
                int b = batch[n];
                v = (lane < 12) ? case_p[b * 4 + (lane - 8)]
                                : bc_p[b * 4 + (lane - 12)];
            }
            in_sh[slot * 17 + lane] = v;
        }
    }
    __syncthreads();

    float acc[16];
#pragma unroll
    for (int c = 0; c < 16; ++c) acc[c] = b1[wb + c];
    for (int k = 0; k < 16; ++k) {
        float a = in_sh[lane * 17 + k];
        const float4* wr = (const float4*)(W1 + k * 64 + wb);
        float4 w0 = wr[0], w1 = wr[1], w2 = wr[2], w3 = wr[3];
        acc[0]  = fmaf(a, w0.x, acc[0]);  acc[1]  = fmaf(a, w0.y, acc[1]);
        acc[2]  = fmaf(a, w0.z, acc[2]);  acc[3]  = fmaf(a, w0.w, acc[3]);
        acc[4]  = fmaf(a, w1.x, acc[4]);  acc[5]  = fmaf(a, w1.y, acc[5]);
        acc[6]  = fmaf(a, w1.z, acc[6]);  acc[7]  = fmaf(a, w1.w, acc[7]);
        acc[8]  = fmaf(a, w2.x, acc[8]);  acc[9]  = fmaf(a, w2.y, acc[9]);
        acc[10] = fmaf(a, w2.z, acc[10]); acc[11] = fmaf(a, w2.w, acc[11]);
        acc[12] = fmaf(a, w3.x, acc[12]); acc[13] = fmaf(a, w3.y, acc[13]);
        acc[14] = fmaf(a, w3.z, acc[14]); acc[15] = fmaf(a, w3.w, acc[15]);
    }
#pragma unroll
    for (int c = 0; c < 16; ++c) m1_sh[lane * 65 + wb + c] = silu_f(acc[c]);
    __syncthreads();

    float acc2[16];
#pragma unroll
    for (int c = 0; c < 16; ++c) acc2[c] = b2[wb + c];
    for (int k = 0; k < 64; ++k) {
        float a = m1_sh[lane * 65 + k];
        const float4* wr = (const float4*)(W2 + k * 64 + wb);
        float4 w0 = wr[0], w1 = wr[1], w2 = wr[2], w3 = wr[3];
        acc2[0]  = fmaf(a, w0.x, acc2[0]);  acc2[1]  = fmaf(a, w0.y, acc2[1]);
        acc2[2]  = fmaf(a, w0.z, acc2[2]);  acc2[3]  = fmaf(a, w0.w, acc2[3]);
        acc2[4]  = fmaf(a, w1.x, acc2[4]);  acc2[5]  = fmaf(a, w1.y, acc2[5]);
        acc2[6]  = fmaf(a, w1.z, acc2[6]);  acc2[7]  = fmaf(a, w1.w, acc2[7]);
        acc2[8]  = fmaf(a, w2.x, acc2[8]);  acc2[9]  = fmaf(a, w2.y, acc2[9]);
        acc2[10] = fmaf(a, w2.z, acc2[10]); acc2[11] = fmaf(a, w2.w, acc2[11]);
        acc2[12] = fmaf(a, w3.x, acc2[12]); acc2[13] = fmaf(a, w3.y, acc2[13]);
        acc2[14] = fmaf(a, w3.z, acc2[14]); acc2[15] = fmaf(a, w3.w, acc2[15]);
    }

    float s1 = 0.f, s2 = 0.f;
#pragma unroll
    for (int c = 0; c < 16; ++c) { s1 += acc2[c]; s2 += acc2[c] * acc2[c]; }
    red_sh[w * 64 + lane] = s1;
    red_sh[256 + w * 64 + lane] = s2;
    __syncthreads();
    float t1 = 0.f, t2 = 0.f;
#pragma unroll
    for (int j = 0; j < 4; ++j) {
        t1 += red_sh[j * 64 + lane];
        t2 += red_sh[256 + j * 64 + lane];
    }
    float mean = t1 * (1.0f / 64.0f);
    float var  = t2 * (1.0f / 64.0f) - mean * mean;
    float rstd = rsqrtf(var + 1e-5f);

    int n = n0 + lane;
    if (n < NN) {
        float vals[16];
#pragma unroll
        for (int c = 0; c < 16; ++c) {
            int ch = wb + c;
            vals[c] = (acc2[c] - mean) * rstd * g[ch] + be[ch];
            h[n * 64 + ch] = vals[c];
        }
        uint4 p0, p1;
        p0.x = pack_bf16x2(vals[0], vals[1]);   p0.y = pack_bf16x2(vals[2], vals[3]);
        p0.z = pack_bf16x2(vals[4], vals[5]);   p0.w = pack_bf16x2(vals[6], vals[7]);
        p1.x = pack_bf16x2(vals[8], vals[9]);   p1.y = pack_bf16x2(vals[10], vals[11]);
        p1.z = pack_bf16x2(vals[12], vals[13]); p1.w = pack_bf16x2(vals[14], vals[15]);
        *(uint4*)(h2 + (size_t)n * 32 + w * 8)     = p0;
        *(uint4*)(h2 + (size_t)n * 32 + w * 8 + 4) = p1;
    }
}

// ---------------------------------------------------------------------------
// Edge MLP via MFMA + segmented scatter-add over dst-sorted edges.
// XCD-aware block swizzle. ks=4 B-fragment comes STRAIGHT from registers:
// quad0 uses ea_pk[e] (coalesced uint4 load), quads 1-3 use a zero fragment
// (A is zero-padded for k>=133 so only finiteness matters). This drops the
// ea/zero LDS region: row stride 84->68 words, LDS 21504->17408 B ->
// 8 blocks/CU (100% wave occupancy). Staging via b128. DPP scan with
// fmaf-mask merge. MID aliases B1 (wave-local DS ordering). No __syncthreads.
// ---------------------------------------------------------------------------
__global__ __launch_bounds__(256, 8) void edge_kernel(
    const unsigned int* __restrict__ h2,
    const int* __restrict__ sdst, const int* __restrict__ ssrc,
    const uint4* __restrict__ ea_pk,
    const short* __restrict__ W1pk, const float* __restrict__ b1,
    const short* __restrict__ W2pk, const float* __restrict__ b2,
    const float* __restrict__ g, const float* __restrict__ be,
    float* __restrict__ agg)
{
    __shared__ unsigned int lds[4 * 1088];
    const int lane = threadIdx.x & 63;
    const int w    = threadIdx.x >> 6;
    const int quad = lane >> 4;
    const int l15  = lane & 15;
    // XCD swizzle: 25000 blocks = 8 XCDs x 3125 contiguous tiles
    const int tile = (blockIdx.x & 7) * 3125 + (blockIdx.x >> 3);
    const int e0   = tile * 64 + w * 16;           // this wave's 16 edges
    unsigned int* B1  = lds + w * 1088;            // 16 rows x 68 words
    unsigned int* MID = B1;                        // aliased; stride 36

    // ea fragment (k=128..135) for quad0; zeros for quads 1-3 (k=136..159)
    union { uint4 u; bf16x8 b; } eacv;
    eacv.u = ea_pk[e0 + l15];
    const bf16x8 zfrag = {0, 0, 0, 0, 0, 0, 0, 0};
    const bf16x8 ks4frag = (quad == 0) ? eacv.b : zfrag;

    // stage h2 rows: 32 half-rows (edge x {dst,src}) x 8 uint4; 4 iters b128
#pragma unroll
    for (int i = 0; i < 4; ++i) {
        int hr   = i * 8 + (lane >> 3);            // half-row 0..31
        int p    = e0 + (hr >> 1);
        int node = (hr & 1) ? ssrc[p] : sdst[p];
        int w4   = (lane & 7) * 4;
        uint4 v = *(const uint4*)(h2 + (size_t)node * 32 + w4);
        *(uint4*)(B1 + (hr >> 1) * 68 + (hr & 1) * 32 + w4) = v;
    }

    // GEMM1: C1^T[ch][edge], K=160 (ks 0..3 from LDS, ks=4 from registers)
    f32x4 acc1[4] = {{0,0,0,0},{0,0,0,0},{0,0,0,0},{0,0,0,0}};
    const unsigned int* brow = B1 + l15 * 68;
    for (int ks = 0; ks < 4; ++ks) {
        bf16x8 bfrag = *(const bf16x8*)(brow + ks * 16 + quad * 4);
        const short* apk = W1pk + (size_t)(ks * 4) * 512 + lane * 8;
#pragma unroll
        for (int mt = 0; mt < 4; ++mt) {
            bf16x8 afrag = *(const bf16x8*)(apk + mt * 512);
            acc1[mt] = __builtin_amdgcn_mfma_f32_16x16x32_bf16(
                afrag, bfrag, acc1[mt], 0, 0, 0);
        }
    }
    {
        const short* apk = W1pk + (size_t)(4 * 4) * 512 + lane * 8;
#pragma unroll
        for (int mt = 0; mt < 4; ++mt) {
            bf16x8 afrag = *(const bf16x8*)(apk + mt * 512);
            acc1[mt] = __builtin_amdgcn_mfma_f32_16x16x32_bf16(
                afrag, ks4frag, acc1[mt], 0, 0, 0);
        }
    }
    // epilogue 1: bias + silu -> MID (aliased over B1; all B1 reads complete)
#pragma unroll
    for (int mt = 0; mt < 4; ++mt) {
        int ch0 = mt * 16 + quad * 4;
        float v0 = silu_f(acc1[mt][0] + b1[ch0 + 0]);
        float v1 = silu_f(acc1[mt][1] + b1[ch0 + 1]);
        float v2 = silu_f(acc1[mt][2] + b1[ch0 + 2]);
        float v3 = silu_f(acc1[mt][3] + b1[ch0 + 3]);
        uint2 pk;
        pk.x = pack_bf16x2(v0, v1);
        pk.y = pack_bf16x2(v2, v3);
        *(uint2*)(MID + l15 * 36 + mt * 8 + quad * 2) = pk;
    }

    // GEMM2: C2^T[ch][edge], K=64 (2 ks)
    f32x4 acc2[4] = {{0,0,0,0},{0,0,0,0},{0,0,0,0},{0,0,0,0}};
    const unsigned int* mrow = MID + l15 * 36;
    for (int ks = 0; ks < 2; ++ks) {
        bf16x8 bfrag = *(const bf16x8*)(mrow + ks * 16 + quad * 4);
        const short* apk = W2pk + (size_t)(ks * 4) * 512 + lane * 8;
#pragma unroll
        for (int mt = 0; mt < 4; ++mt) {
            bf16x8 afrag = *(const bf16x8*)(apk + mt * 512);
            acc2[mt] = __builtin_amdgcn_mfma_f32_16x16x32_bf16(
                afrag, bfrag, acc2[mt], 0, 0, 0);
        }
    }

    // bias + LN over the 64 channels of this lane's edge
    float vals[16];
    float s1 = 0.f, s2 = 0.f;
#pragma unroll
    for (int mt = 0; mt < 4; ++mt) {
#pragma unroll
        for (int r = 0; r < 4; ++r) {
            int ch = mt * 16 + quad * 4 + r;
            float vv = acc2[mt][r] + b2[ch];
            vals[mt * 4 + r] = vv;
            s1 += vv; s2 += vv * vv;
        }
    }
    s1 += __shfl_xor(s1, 16); s1 += __shfl_xor(s1, 32);
    s2 += __shfl_xor(s2, 16); s2 += __shfl_xor(s2, 32);
    float mean = s1 * (1.0f / 64.0f);
    float var  = s2 * (1.0f / 64.0f) - mean * mean;
    float rstd = rsqrtf(var + 1e-5f);
#pragma unroll
    for (int mt = 0; mt < 4; ++mt) {
#pragma unroll
        for (int r = 0; r < 4; ++r) {
            int ch = mt * 16 + quad * 4 + r;
            vals[mt * 4 + r] = (vals[mt * 4 + r] - mean) * rstd * g[ch] + be[ch];
        }
    }

    // segmented inclusive scan over the wave's 16 edges (l15 dimension),
    // DPP row_shr; merge via fmaf with one cndmask-derived mask per step.
    int d_l = sdst[e0 + l15];
#define SEG_STEP(CTRL)                                                        \
    {                                                                         \
        int d_up = dpp_i<CTRL>(-1, d_l);                                      \
        float msk = (d_up == d_l) ? 1.0f : 0.0f;                              \
        _Pragma("unroll")                                                     \
        for (int c = 0; c < 16; ++c) {                                        \
            float vu = __int_as_float(dpp_i<CTRL>(0, __float_as_int(vals[c])));\
            vals[c] = fmaf(vu, msk, vals[c]);                                 \
        }                                                                     \
    }
    SEG_STEP(0x111)   // row_shr:1
    SEG_STEP(0x112)   // row_shr:2
    SEG_STEP(0x114)   // row_shr:4
    SEG_STEP(0x118)   // row_shr:8
#undef SEG_STEP
    int d_next = dpp_i<0x101>(-1, d_l);   // row_shl:1 -> lane i gets i+1; lane15 -> -1
    bool last = (d_next != d_l);
    if (last) {
#pragma unroll
        for (int mt = 0; mt < 4; ++mt) {
#pragma unroll
            for (int r = 0; r < 4; ++r) {
                int ch = mt * 16 + quad * 4 + r;
                atomicAdd(&agg[(size_t)d_l * 64 + ch], vals[mt * 4 + r]);
            }
        }
    }
}

// ---------------------------------------------------------------------------
// Node MLP via MFMA + residual: h = h + LN(silu([h,agg]@W1+b1)@W2+b2)
// uint4/float4 staging; no __syncthreads. Updates h and h2.
// ---------------------------------------------------------------------------
__global__ __launch_bounds__(256, 6) void node_kernel(
    float* __restrict__ h, unsigned int* __restrict__ h2,
    const float* __restrict__ agg,
    const short* __restrict__ W1pk, const float* __restrict__ b1,
    const short* __restrict__ W2pk, const float* __restrict__ b2,
    const float* __restrict__ g, const float* __restrict__ be)
{
    __shared__ unsigned int lds[4 * 1088];
    const int lane = threadIdx.x & 63;
    const int w    = threadIdx.x >> 6;
    const int quad = lane >> 4;
    const int l15  = lane & 15;
    const int n0   = blockIdx.x * 64 + w * 16;     // this wave's 16 nodes
    unsigned int* B1  = lds + w * 1088;            // 16 rows x 68 words
    unsigned int* MID = B1;                        // aliased; stride 36

    // stage h2 rows (words 0..31): 16 rows x 8 uint4; 2 iters
#pragma unroll
    for (int i = 0; i < 2; ++i) {
        int row = i * 8 + (lane >> 3);
        int n = n0 + row; if (n >= NN) n = NN - 1;
        int w4 = (lane & 7) * 4;
        uint4 v = *(const uint4*)(h2 + (size_t)n * 32 + w4);
        *(uint4*)(B1 + row * 68 + w4) = v;
    }
    // stage agg (fp32 -> bf16, words 32..63): 16 rows x 16 float4; 4 iters
#pragma unroll
    for (int i = 0; i < 4; ++i) {
        int row = i * 4 + (lane >> 4);
        int n = n0 + row; if (n >= NN) n = NN - 1;
        int f4 = lane & 15;
        float4 v = *(const float4*)(agg + (size_t)n * 64 + f4 * 4);
        uint2 pk;
        pk.x = pack_bf16x2(v.x, v.y);
        pk.y = pack_bf16x2(v.z, v.w);
        *(uint2*)(B1 + row * 68 + 32 + f4 * 2) = pk;
    }

    // GEMM1: K=128 (4 ks)
    f32x4 acc1[4] = {{0,0,0,0},{0,0,0,0},{0,0,0,0},{0,0,0,0}};
    const unsigned int* brow = B1 + l15 * 68;
    for (int ks = 0; ks < 4; ++ks) {
        bf16x8 bfrag = *(const bf16x8*)(brow + ks * 16 + quad * 4);
        const short* apk = W1pk + (size_t)(ks * 4) * 512 + lane * 8;
#pragma unroll
        for (int mt = 0; mt < 4; ++mt) {
            bf16x8 afrag = *(const bf16x8*)(apk + mt * 512);
            acc1[mt] = __builtin_amdgcn_mfma_f32_16x16x32_bf16(
                afrag, bfrag, acc1[mt], 0, 0, 0);
        }
    }
#pragma unroll
    for (int mt = 0; mt < 4; ++mt) {
        int ch0 = mt * 16 + quad * 4;
        float v0 = silu_f(acc1[mt][0] + b1[ch0 + 0]);
        float v1 = silu_f(acc1[mt][1] + b1[ch0 + 1]);
        float v2 = silu_f(acc1[mt][2] + b1[ch0 + 2]);
        float v3 = silu_f(acc1[mt][3] + b1[ch0 + 3]);
        uint2 pk;
        pk.x = pack_bf16x2(v0, v1);
        pk.y = pack_bf16x2(v2, v3);
        *(uint2*)(MID + l15 * 36 + mt * 8 + quad * 2) = pk;
    }

    // GEMM2: K=64 (2 ks)
    f32x4 acc2[4] = {{0,0,0,0},{0,0,0,0},{0,0,0,0},{0,0,0,0}};
    const unsigned int* mrow = MID + l15 * 36;
    for (int ks = 0; ks < 2; ++ks) {
        bf16x8 bfrag = *(const bf16x8*)(mrow + ks * 16 + quad * 4);
        const short* apk = W2pk + (size_t)(ks * 4) * 512 + lane * 8;
#pragma unroll
        for (int mt = 0; mt < 4; ++mt) {
            bf16x8 afrag = *(const bf16x8*)(apk + mt * 512);
            acc2[mt] = __builtin_amdgcn_mfma_f32_16x16x32_bf16(
                afrag, bfrag, acc2[mt], 0, 0, 0);
        }
    }

    // bias + LN over the 64 channels of this lane's node
    float vals[16];
    float s1 = 0.f, s2 = 0.f;
#pragma unroll
    for (int mt = 0; mt < 4; ++mt) {
#pragma unroll
        for (int r = 0; r < 4; ++r) {
            int ch = mt * 16 + quad * 4 + r;
            float vv = acc2[mt][r] + b2[ch];
            vals[mt * 4 + r] = vv;
            s1 += vv; s2 += vv * vv;
        }
    }
    s1 += __shfl_xor(s1, 16); s1 += __shfl_xor(s1, 32);
    s2 += __shfl_xor(s2, 16); s2 += __shfl_xor(s2, 32);
    float mean = s1 * (1.0f / 64.0f);
    float var  = s2 * (1.0f / 64.0f) - mean * mean;
    float rstd = rsqrtf(var + 1e-5f);

    int n = n0 + l15;
    if (n < NN) {
#pragma unroll
        for (int mt = 0; mt < 4; ++mt) {
            int ch0 = mt * 16 + quad * 4;
            float4 hv = *(const float4*)(h + (size_t)n * 64 + ch0);
            float o0 = hv.x + (vals[mt*4+0] - mean) * rstd * g[ch0+0] + be[ch0+0];
            float o1 = hv.y + (vals[mt*4+1] - mean) * rstd * g[ch0+1] + be[ch0+1];
            float o2 = hv.z + (vals[mt*4+2] - mean) * rstd * g[ch0+2] + be[ch0+2];
            float o3 = hv.w + (vals[mt*4+3] - mean) * rstd * g[ch0+3] + be[ch0+3];
            float4 st = {o0, o1, o2, o3};
            *(float4*)(h + (size_t)n * 64 + ch0) = st;
            uint2 pk;
            pk.x = pack_bf16x2(o0, o1);
            pk.y = pack_bf16x2(o2, o3);
            *(uint2*)(h2 + (size_t)n * 32 + mt * 8 + quad * 2) = pk;
        }
    }
}

// ---------------------------------------------------------------------------
// Local decoder via MFMA: out_local = silu(h @ W1 + b1) @ W2 + b2 -> [NN, 6]
// ---------------------------------------------------------------------------
__global__ __launch_bounds__(256, 7) void dec_local_kernel(
    const unsigned int* __restrict__ h2,
    const short* __restrict__ W1pk, const float* __restrict__ b1,
    const short* __restrict__ W2pk, const float* __restrict__ b2,
    float* __restrict__ out)
{
    __shared__ unsigned int lds[4 * 576];
    const int lane = threadIdx.x & 63;
    const int w    = threadIdx.x >> 6;
    const int quad = lane >> 4;
    const int l15  = lane & 15;
    const int n0   = blockIdx.x * 64 + w * 16;
    unsigned int* B1  = lds + w * 576;             // 16 rows x 36 words
    unsigned int* MID = B1;                        // aliased; stride 36

    // stage h2: 16 rows x 8 uint4; 2 iters
#pragma unroll
    for (int i = 0; i < 2; ++i) {
        int row = i * 8 + (lane >> 3);
        int n = n0 + row; if (n >= NN) n = NN - 1;
        int w4 = (lane & 7) * 4;
        uint4 v = *(const uint4*)(h2 + (size_t)n * 32 + w4);
        *(uint4*)(B1 + row * 36 + w4) = v;
    }

    // GEMM1: K=64 (2 ks), M=64 (4 mt)
    f32x4 acc1[4] = {{0,0,0,0},{0,0,0,0},{0,0,0,0},{0,0,0,0}};
    const unsigned int* brow = B1 + l15 * 36;
    for (int ks = 0; ks < 2; ++ks) {
        bf16x8 bfrag = *(const bf16x8*)(brow + ks * 16 + quad * 4);
        const short* apk = W1pk + (size_t)(ks * 4) * 512 + lane * 8;
#pragma unroll
        for (int mt = 0; mt < 4; ++mt) {
            bf16x8 afrag = *(const bf16x8*)(apk + mt * 512);
            acc1[mt] = __builtin_amdgcn_mfma_f32_16x16x32_bf16(
                afrag, bfrag, acc1[mt], 0, 0, 0);
        }
    }
    // epilogue: bias + silu -> MID (bf16)
#pragma unroll
    for (int mt = 0; mt < 4; ++mt) {
        int ch0 = mt * 16 + quad * 4;
        float v0 = silu_f(acc1[mt][0] + b1[ch0 + 0]);
        float v1 = silu_f(acc1[mt][1] + b1[ch0 + 1]);
        float v2 = silu_f(acc1[mt][2] + b1[ch0 + 2]);
        float v3 = silu_f(acc1[mt][3] + b1[ch0 + 3]);
        uint2 pk;
        pk.x = pack_bf16x2(v0, v1);
        pk.y = pack_bf16x2(v2, v3);
        *(uint2*)(MID + l15 * 36 + mt * 8 + quad * 2) = pk;
    }

    // GEMM2: K=64 (2 ks), M=16 (out padded 6->16)
    f32x4 acc2 = {0, 0, 0, 0};
    const unsigned int* mrow = MID + l15 * 36;
    for (int ks = 0; ks < 2; ++ks) {
        bf16x8 bfrag = *(const bf16x8*)(mrow + ks * 16 + quad * 4);
        bf16x8 afrag = *(const bf16x8*)(W2pk + (size_t)ks * 512 + lane * 8);
        acc2 = __builtin_amdgcn_mfma_f32_16x16x32_bf16(afrag, bfrag, acc2, 0, 0, 0);
    }

    int n = n0 + l15;
    if (n < NN && quad < 2) {
#pragma unroll
        for (int r = 0; r < 4; ++r) {
            int ch = quad * 4 + r;
            if (ch < 6) out[(size_t)n * 6 + ch] = acc2[r] + b2[ch];
        }
    }
}

// ---------------------------------------------------------------------------
// Pooling: pooled[g][c] = sum_{batch[n]==g} h[n][c];  cnt[g] = count
// ---------------------------------------------------------------------------
__global__ __launch_bounds__(256) void pool_kernel(
    const float* __restrict__ h, const int* __restrict__ batch,
    float* __restrict__ pooled, float* __restrict__ cnt)
{
    const int c   = threadIdx.x & 63;
    const int rep = blockIdx.x * 4 + (threadIdx.x >> 6);   // 1024 reps
    float acc[NG] = {0.f, 0.f, 0.f, 0.f};
    float cl[NG]  = {0.f, 0.f, 0.f, 0.f};
    for (int n = rep; n < NN; n += 1024) {
        int b = batch[n];
        float v = h[n * 64 + c];
#pragma unroll
        for (int gph = 0; gph < NG; ++gph) {
            if (b == gph) { acc[gph] += v; cl[gph] += 1.0f; }
        }
    }
#pragma unroll
    for (int gph = 0; gph < NG; ++gph) {
        atomicAdd(&pooled[gph * 64 + c], acc[gph]);
        if (c == 0) atomicAdd(&cnt[gph], cl[gph]);
    }
}

// ---------------------------------------------------------------------------
// Global decoder: out_global = silu(mean_pool @ W1 + b1) @ W2 + b2 -> [4,4]
// ---------------------------------------------------------------------------
__global__ __launch_bounds__(256) void dec_global_kernel(
    const float* __restrict__ pooled, const float* __restrict__ cnt,
    const float* __restrict__ W1, const float* __restrict__ b1,
    const float* __restrict__ W2, const float* __restrict__ b2,
    float* __restrict__ out)
{
    __shared__ float mid_sh[4][32];
    const int lane = threadIdx.x & 63;
    const int gph  = threadIdx.x >> 6;
    float inv = 1.0f / fmaxf(cnt[gph], 1.0f);
    if (lane < 32) {
        float a = b1[lane];
        for (int k = 0; k < 64; ++k)
            a = fmaf(pooled[gph * 64 + k] * inv, W1[k * 32 + lane], a);
        mid_sh[gph][lane] = silu_f(a);
    }
    __syncthreads();
    if (lane < 4) {
        float o = b2[lane];
        for (int k = 0; k < 32; ++k)
            o = fmaf(mid_sh[gph][k], W2[k * 4 + lane], o);
        out[gph * 4 + lane] = o;
    }
}

// ---------------------------------------------------------------------------
extern "C" void kernel_launch(void* const* d_in, const int* in_sizes, int n_in,
                              void* d_out, int out_size, void* d_ws, size_t ws_size,
                              hipStream_t stream)
{
    const float* x      = (const float*)d_in[0];
    const int*   ei     = (const int*)  d_in[1];
    const float* ea     = (const float*)d_in[2];
    const int*   batch  = (const int*)  d_in[3];
    const float* case_p = (const float*)d_in[4];
    const float* bc_p   = (const float*)d_in[5];
    const float* enc_W1 = (const float*)d_in[6];
    const float* enc_b1 = (const float*)d_in[7];
    const float* enc_W2 = (const float*)d_in[8];
    const float* enc_b2 = (const float*)d_in[9];
    const float* enc_g  = (const float*)d_in[10];
    const float* enc_be = (const float*)d_in[11];
    const float* eW1    = (const float*)d_in[12];
    const float* eb1    = (const float*)d_in[13];
    const float* eW2    = (const float*)d_in[14];
    const float* eb2    = (const float*)d_in[15];
    const float* eg     = (const float*)d_in[16];
    const float* ebe    = (const float*)d_in[17];
    const float* nW1    = (const float*)d_in[18];
    const float* nb1    = (const float*)d_in[19];
    const float* nW2    = (const float*)d_in[20];
    const float* nb2    = (const float*)d_in[21];
    const float* ng     = (const float*)d_in[22];
    const float* nbe    = (const float*)d_in[23];
    const float* dlW1   = (const float*)d_in[24];
    const float* dlb1   = (const float*)d_in[25];
    const float* dlW2   = (const float*)d_in[26];
    const float* dlb2   = (const float*)d_in[27];
    const float* dgW1   = (const float*)d_in[28];
    const float* dgb1   = (const float*)d_in[29];
    const float* dgW2   = (const float*)d_in[30];
    const float* dgb2   = (const float*)d_in[31];

    float* out = (float*)d_out;

    char* ws = (char*)d_ws;
    size_t off_b = 0;
    auto alloc = [&](size_t bytes) {
        void* p = ws + off_b;
        off_b = (off_b + bytes + 255) & ~(size_t)255;
        return p;
    };
    const size_t hBytes = (size_t)NN * H * sizeof(float);     // 12.8 MB
    float*        h      = (float*)alloc(hBytes);
    float*        agg    = (float*)alloc(hBytes);
    unsigned int* h2     = (unsigned int*)alloc((size_t)NN * 32 * 4);  // bf16 mirror
    float*        pooled = (float*)alloc(256 * sizeof(float));
    float*        cnt    = (float*)alloc(4 * sizeof(float));
    int*          deg    = (int*)alloc((NN + 1) * sizeof(int));
    int*          offs   = (int*)alloc((NN + 1) * sizeof(int));
    int*          cursor = (int*)alloc((NN + 1) * sizeof(int));
    int*          bsum   = (int*)alloc(64 * sizeof(int));
    int*          bbase  = (int*)alloc(64 * sizeof(int));
    int*          sidx   = (int*)alloc((size_t)NE * sizeof(int));
    int*          sdst   = (int*)alloc((size_t)NE * sizeof(int));
    int*          ssrc   = (int*)alloc((size_t)NE * sizeof(int));
    uint4*        ea_pk  = (uint4*)alloc((size_t)NE * sizeof(uint4));  // 25.6 MB
    short*        eW1pk  = (short*)alloc((size_t)NL * 10240 * sizeof(short));
    short*        eW2pk  = (short*)alloc((size_t)NL * 4096 * sizeof(short));
    short*        nW1pk  = (short*)alloc((size_t)NL * 8192 * sizeof(short));
    short*        nW2pk  = (short*)alloc((size_t)NL * 4096 * sizeof(short));
    short*        dlW1pk = (short*)alloc(4096 * sizeof(short));
    short*        dlW2pk = (short*)alloc(1024 * sizeof(short));

    hipMemsetAsync(pooled, 0, (256 + 4 + 64) * sizeof(float), stream);
    hipMemsetAsync(deg, 0, (NN + 1) * sizeof(int), stream);

    const int NB = (NN + 1023) / 1024;   // 49
    degree_kernel<<<(NE + 255) / 256, 256, 0, stream>>>(ei, deg);
    scan1_kernel<<<NB, 1024, 0, stream>>>(deg, offs, bsum);
    scan2_kernel<<<1, 64, 0, stream>>>(bsum, bbase, NB);
    scan3_kernel<<<NB, 1024, 0, stream>>>(offs, bbase, cursor);
    scatter_kernel<<<(NE + 255) / 256, 256, 0, stream>>>(ei, cursor, sidx, sdst, ssrc);
    ea_pack_kernel<<<(NE + 255) / 256, 256, 0, stream>>>(ea, sidx, ea_pk);
    pack_weights_kernel<<<dim3(124, NL), 256, 0, stream>>>(
        eW1, eW2, nW1, nW2, dlW1, dlW2,
        eW1pk, eW2pk, nW1pk, nW2pk, dlW1pk, dlW2pk);

    const int nodeBlocks = (NN + 63) / 64;    // 782
    encoder_kernel<<<nodeBlocks, 256, 0, stream>>>(
        x, batch, case_p, bc_p, enc_W1, enc_b1, enc_W2, enc_b2, enc_g, enc_be,
        h, h2);

    for (int l = 0; l < NL; ++l) {
        hipMemsetAsync(agg, 0, hBytes, stream);
        edge_kernel<<<NE / 64, 256, 0, stream>>>(
            h2, sdst, ssrc, ea_pk,
            eW1pk + (size_t)l * 10240, eb1 + l * H,
            eW2pk + (size_t)l * 4096,  eb2 + l * H,
            eg + l * H, ebe + l * H, agg);
        node_kernel<<<nodeBlocks, 256, 0, stream>>>(
            h, h2, agg,
            nW1pk + (size_t)l * 8192, nb1 + l * H,
            nW2pk + (size_t)l * 4096, nb2 + l * H,
            ng + l * H, nbe + l * H);
    }

    dec_local_kernel<<<nodeBlocks, 256, 0, stream>>>(
        h2, dlW1pk, dlb1, dlW2pk, dlb2, out);
    pool_kernel<<<256, 256, 0, stream>>>(h, batch, pooled, cnt);
    dec_global_kernel<<<1, 256, 0, stream>>>(pooled, cnt, dgW1, dgb1, dgW2, dgb2,
                                             out + (size_t)NN * 6);
}

// Round 12
// 1555.128 us; speedup vs baseline: 1.1091x; 1.1091x over previous
//
#include <hip/hip_runtime.h>
#include <cmath>

// Problem constants (from reference)
constexpr int NN = 50000;      // nodes
constexpr int NE = 1600000;    // edges
constexpr int H  = 64;         // hidden
constexpr int NL = 5;          // layers
constexpr int NG = 4;          // graphs
constexpr int EIN = 2 * H + 5; // 133
constexpr int NIN = 2 * H;     // 128

typedef short bf16x8 __attribute__((ext_vector_type(8)));
typedef float f32x4  __attribute__((ext_vector_type(4)));

__device__ __forceinline__ float silu_f(float x) {
    return x / (1.0f + __expf(-x));
}

// round-to-nearest-even fp32 -> bf16 bits
__device__ __forceinline__ unsigned int f2bf(float f) {
    unsigned int u = __float_as_uint(f);
    u += 0x7fffu + ((u >> 16) & 1u);
    return u >> 16;
}
__device__ __forceinline__ unsigned int pack_bf16x2(float x, float y) {
    return f2bf(x) | (f2bf(y) << 16);
}

// DPP lane-shift within 16-lane rows (VALU pipe, not ds_bpermute).
// row_shr:N = 0x110|N (lane i <- lane i-N within row); row_shl:1 = 0x101.
// bound_ctrl=false: out-of-row lanes keep `old`.
template <int CTRL>
__device__ __forceinline__ int dpp_i(int old, int v) {
    return __builtin_amdgcn_update_dpp(old, v, CTRL, 0xF, 0xF, false);
}

// ---------------------------------------------------------------------------
// Counting sort of edges by dst
// ---------------------------------------------------------------------------
__global__ __launch_bounds__(256) void degree_kernel(
    const int* __restrict__ ei, int* __restrict__ deg)
{
    int e = blockIdx.x * 256 + threadIdx.x;
    if (e < NE) atomicAdd(&deg[ei[NE + e]], 1);
}

// Hierarchical exclusive scan: 49 parallel block scans -> 1-wave scan of
// block sums -> add block bases.
__global__ __launch_bounds__(1024) void scan1_kernel(
    const int* __restrict__ deg, int* __restrict__ off, int* __restrict__ bsum)
{
    __shared__ int sh[1024];
    const int tid = threadIdx.x;
    int i = blockIdx.x * 1024 + tid;
    int v = (i < NN) ? deg[i] : 0;
    sh[tid] = v;
    __syncthreads();
    for (int d = 1; d < 1024; d <<= 1) {
        int t = (tid >= d) ? sh[tid - d] : 0;
        __syncthreads();
        sh[tid] += t;
        __syncthreads();
    }
    if (i < NN) off[i] = sh[tid] - v;          // block-local exclusive
    if (tid == 1023) bsum[blockIdx.x] = sh[1023];
}

__global__ __launch_bounds__(64) void scan2_kernel(
    const int* __restrict__ bsum, int* __restrict__ bbase, int nb)
{
    int lane = threadIdx.x;
    int v = (lane < nb) ? bsum[lane] : 0;
    int orig = v;
    for (int d = 1; d < 64; d <<= 1) {
        int t = __shfl_up(v, d);
        if (lane >= d) v += t;
    }
    bbase[lane] = v - orig;                    // exclusive
}

__global__ __launch_bounds__(1024) void scan3_kernel(
    int* __restrict__ off, const int* __restrict__ bbase,
    int* __restrict__ cursor)
{
    int i = blockIdx.x * 1024 + threadIdx.x;
    if (i < NN) {
        int o = off[i] + bbase[blockIdx.x];
        off[i] = o;
        cursor[i] = o;
        if (i == NN - 1) off[NN] = NE;
    }
}

__global__ __launch_bounds__(256) void scatter_kernel(
    const int* __restrict__ ei, int* __restrict__ cursor,
    int* __restrict__ sidx, int* __restrict__ sdst, int* __restrict__ ssrc)
{
    int e = blockIdx.x * 256 + threadIdx.x;
    if (e < NE) {
        int d = ei[NE + e];
        int p = atomicAdd(&cursor[d], 1);
        sidx[p] = e;
        sdst[p] = d;
        ssrc[p] = ei[e];
    }
}

// ---------------------------------------------------------------------------
// Pre-pack edge_attr into sorted-edge order, bf16, 16B/edge (5 vals + 3 zero).
// This IS the MFMA B-fragment for (ks=4, quad=0): k=128..135 = {ea0..ea4,0,0,0}.
// ---------------------------------------------------------------------------
__global__ __launch_bounds__(256) void ea_pack_kernel(
    const float* __restrict__ ea, const int* __restrict__ sidx,
    uint4* __restrict__ ea_pk)
{
    int p = blockIdx.x * 256 + threadIdx.x;
    if (p < NE) {
        const float* s = ea + (size_t)sidx[p] * 5;
        uint4 v;
        v.x = pack_bf16x2(s[0], s[1]);
        v.y = pack_bf16x2(s[2], s[3]);
        v.z = pack_bf16x2(s[4], 0.0f);
        v.w = 0u;
        ea_pk[p] = v;
    }
}

// ---------------------------------------------------------------------------
// Pre-pack MLP weights into MFMA A-fragment order (bf16).
// elem(ks, mt, lane, j) = W[k = ks*32 + (lane>>4)*8 + j][ch = mt*16 + (lane&15)]
// ---------------------------------------------------------------------------
__global__ __launch_bounds__(256) void pack_weights_kernel(
    const float* __restrict__ eW1, const float* __restrict__ eW2,
    const float* __restrict__ nW1, const float* __restrict__ nW2,
    const float* __restrict__ dlW1, const float* __restrict__ dlW2,
    short* __restrict__ eW1pk, short* __restrict__ eW2pk,
    short* __restrict__ nW1pk, short* __restrict__ nW2pk,
    short* __restrict__ dlW1pk, short* __restrict__ dlW2pk)
{
    int l = blockIdx.y;
    int t = blockIdx.x * 256 + threadIdx.x;
    if (t < 10240) {
        int j = t & 7, lane = (t >> 3) & 63, mt = (t >> 9) & 3, ks = t >> 11;
        int k  = ks * 32 + (lane >> 4) * 8 + j;
        int ch = mt * 16 + (lane & 15);
        float v = (k < EIN) ? eW1[(size_t)l * EIN * H + k * H + ch] : 0.0f;
        eW1pk[(size_t)l * 10240 + t] = (short)f2bf(v);
    } else if (t < 14336) {
        int t2 = t - 10240;
        int j = t2 & 7, lane = (t2 >> 3) & 63, mt = (t2 >> 9) & 3, ks = t2 >> 11;
        int k = ks * 32 + (lane >> 4) * 8 + j;
        int ch = mt * 16 + (lane & 15);
        eW2pk[(size_t)l * 4096 + t2] = (short)f2bf(eW2[(size_t)l * H * H + k * H + ch]);
    } else if (t < 22528) {
        int t3 = t - 14336;
        int j = t3 & 7, lane = (t3 >> 3) & 63, mt = (t3 >> 9) & 3, ks = t3 >> 11;
        int k = ks * 32 + (lane >> 4) * 8 + j;
        int ch = mt * 16 + (lane & 15);
        nW1pk[(size_t)l * 8192 + t3] = (short)f2bf(nW1[(size_t)l * NIN * H + k * H + ch]);
    } else if (t < 26624) {
        int t4 = t - 22528;
        int j = t4 & 7, lane = (t4 >> 3) & 63, mt = (t4 >> 9) & 3, ks = t4 >> 11;
        int k = ks * 32 + (lane >> 4) * 8 + j;
        int ch = mt * 16 + (lane & 15);
        nW2pk[(size_t)l * 4096 + t4] = (short)f2bf(nW2[(size_t)l * H * H + k * H + ch]);
    } else if (t < 30720) {
        if (l == 0) {
            int t5 = t - 26624;
            int j = t5 & 7, lane = (t5 >> 3) & 63, mt = (t5 >> 9) & 3, ks = t5 >> 11;
            int k = ks * 32 + (lane >> 4) * 8 + j;
            int ch = mt * 16 + (lane & 15);
            dlW1pk[t5] = (short)f2bf(dlW1[k * H + ch]);
        }
    } else if (t < 31744) {
        if (l == 0) {
            int t6 = t - 30720;
            int j = t6 & 7, lane = (t6 >> 3) & 63, ks = t6 >> 9;
            int k = ks * 32 + (lane >> 4) * 8 + j;
            int m = lane & 15;
            float v = (m < 6) ? dlW2[k * 6 + m] : 0.0f;
            dlW2pk[t6] = (short)f2bf(v);
        }
    }
}

// ---------------------------------------------------------------------------
// Encoder: h = LN(silu([x, gv[batch]] @ W1 + b1) @ W2 + b2); writes h (fp32)
// and h2 (bf16 mirror used by MFMA staging).
// ---------------------------------------------------------------------------
__global__ __launch_bounds__(256) void encoder_kernel(
    const float* __restrict__ x, const int* __restrict__ batch,
    const float* __restrict__ case_p, const float* __restrict__ bc_p,
    const float* __restrict__ W1, const float* __restrict__ b1,
    const float* __restrict__ W2, const float* __restrict__ b2,
    const float* __restrict__ g, const float* __restrict__ be,
    float* __restrict__ h, unsigned int* __restrict__ h2)
{
    __shared__ float in_sh[64 * 17];
    __shared__ float m1_sh[64 * 65];
    __shared__ float red_sh[2 * 4 * 64];
    const int lane = threadIdx.x & 63;
    const int w    = threadIdx.x >> 6;
    const int wb   = __builtin_amdgcn_readfirstlane(w * 16);
    const int n0   = blockIdx.x * 64;

    for (int i = 0; i < 16; ++i) {
        int slot = w * 16 + i;
        int n = n0 + slot;
        if (n < NN && lane < 16) {
            float v;
            if (lane < 8) v = x[n * 8 + lane];
            else {
                int b = batch[n];
                v = (lane < 12) ? case_p[b * 4 + (lane - 8)]
                                : bc_p[b * 4 + (lane - 12)];
            }
            in_sh[slot * 17 + lane] = v;
        }
    }
    __syncthreads();

    float acc[16];
#pragma unroll
    for (int c = 0; c < 16; ++c) acc[c] = b1[wb + c];
    for (int k = 0; k < 16; ++k) {
        float a = in_sh[lane * 17 + k];
        const float4* wr = (const float4*)(W1 + k * 64 + wb);
        float4 w0 = wr[0], w1 = wr[1], w2 = wr[2], w3 = wr[3];
        acc[0]  = fmaf(a, w0.x, acc[0]);  acc[1]  = fmaf(a, w0.y, acc[1]);
        acc[2]  = fmaf(a, w0.z, acc[2]);  acc[3]  = fmaf(a, w0.w, acc[3]);
        acc[4]  = fmaf(a, w1.x, acc[4]);  acc[5]  = fmaf(a, w1.y, acc[5]);
        acc[6]  = fmaf(a, w1.z, acc[6]);  acc[7]  = fmaf(a, w1.w, acc[7]);
        acc[8]  = fmaf(a, w2.x, acc[8]);  acc[9]  = fmaf(a, w2.y, acc[9]);
        acc[10] = fmaf(a, w2.z, acc[10]); acc[11] = fmaf(a, w2.w, acc[11]);
        acc[12] = fmaf(a, w3.x, acc[12]); acc[13] = fmaf(a, w3.y, acc[13]);
        acc[14] = fmaf(a, w3.z, acc[14]); acc[15] = fmaf(a, w3.w, acc[15]);
    }
#pragma unroll
    for (int c = 0; c < 16; ++c) m1_sh[lane * 65 + wb + c] = silu_f(acc[c]);
    __syncthreads();

    float acc2[16];
#pragma unroll
    for (int c = 0; c < 16; ++c) acc2[c] = b2[wb + c];
    for (int k = 0; k < 64; ++k) {
        float a = m1_sh[lane * 65 + k];
        const float4* wr = (const float4*)(W2 + k * 64 + wb);
        float4 w0 = wr[0], w1 = wr[1], w2 = wr[2], w3 = wr[3];
        acc2[0]  = fmaf(a, w0.x, acc2[0]);  acc2[1]  = fmaf(a, w0.y, acc2[1]);
        acc2[2]  = fmaf(a, w0.z, acc2[2]);  acc2[3]  = fmaf(a, w0.w, acc2[3]);
        acc2[4]  = fmaf(a, w1.x, acc2[4]);  acc2[5]  = fmaf(a, w1.y, acc2[5]);
        acc2[6]  = fmaf(a, w1.z, acc2[6]);  acc2[7]  = fmaf(a, w1.w, acc2[7]);
        acc2[8]  = fmaf(a, w2.x, acc2[8]);  acc2[9]  = fmaf(a, w2.y, acc2[9]);
        acc2[10] = fmaf(a, w2.z, acc2[10]); acc2[11] = fmaf(a, w2.w, acc2[11]);
        acc2[12] = fmaf(a, w3.x, acc2[12]); acc2[13] = fmaf(a, w3.y, acc2[13]);
        acc2[14] = fmaf(a, w3.z, acc2[14]); acc2[15] = fmaf(a, w3.w, acc2[15]);
    }

    float s1 = 0.f, s2 = 0.f;
#pragma unroll
    for (int c = 0; c < 16; ++c) { s1 += acc2[c]; s2 += acc2[c] * acc2[c]; }
    red_sh[w * 64 + lane] = s1;
    red_sh[256 + w * 64 + lane] = s2;
    __syncthreads();
    float t1 = 0.f, t2 = 0.f;
#pragma unroll
    for (int j = 0; j < 4; ++j) {
        t1 += red_sh[j * 64 + lane];
        t2 += red_sh[256 + j * 64 + lane];
    }
    float mean = t1 * (1.0f / 64.0f);
    float var  = t2 * (1.0f / 64.0f) - mean * mean;
    float rstd = rsqrtf(var + 1e-5f);

    int n = n0 + lane;
    if (n < NN) {
        float vals[16];
#pragma unroll
        for (int c = 0; c < 16; ++c) {
            int ch = wb + c;
            vals[c] = (acc2[c] - mean) * rstd * g[ch] + be[ch];
            h[n * 64 + ch] = vals[c];
        }
        uint4 p0, p1;
        p0.x = pack_bf16x2(vals[0], vals[1]);   p0.y = pack_bf16x2(vals[2], vals[3]);
        p0.z = pack_bf16x2(vals[4], vals[5]);   p0.w = pack_bf16x2(vals[6], vals[7]);
        p1.x = pack_bf16x2(vals[8], vals[9]);   p1.y = pack_bf16x2(vals[10], vals[11]);
        p1.z = pack_bf16x2(vals[12], vals[13]); p1.w = pack_bf16x2(vals[14], vals[15]);
        *(uint4*)(h2 + (size_t)n * 32 + w * 8)     = p0;
        *(uint4*)(h2 + (size_t)n * 32 + w * 8 + 4) = p1;
    }
}

// ---------------------------------------------------------------------------
// Edge MLP via MFMA + segmented scatter-add over dst-sorted edges.
// XCD-aware block swizzle. ks=4 B-fragment from registers (ea_pk / zeros);
// LDS 17408 B. launch_bounds (256,7): VGPR budget 73 — R11's (256,8) squeezed
// VGPR to 24 and regressed (ILP collapse); 7 waves keeps registers in flight.
// DPP scan with fmaf-mask merge. MID aliases B1. No __syncthreads.
// ---------------------------------------------------------------------------
__global__ __launch_bounds__(256, 7) void edge_kernel(
    const unsigned int* __restrict__ h2,
    const int* __restrict__ sdst, const int* __restrict__ ssrc,
    const uint4* __restrict__ ea_pk,
    const short* __restrict__ W1pk, const float* __restrict__ b1,
    const short* __restrict__ W2pk, const float* __restrict__ b2,
    const float* __restrict__ g, const float* __restrict__ be,
    float* __restrict__ agg)
{
    __shared__ unsigned int lds[4 * 1088];
    const int lane = threadIdx.x & 63;
    const int w    = threadIdx.x >> 6;
    const int quad = lane >> 4;
    const int l15  = lane & 15;
    // XCD swizzle: 25000 blocks = 8 XCDs x 3125 contiguous tiles
    const int tile = (blockIdx.x & 7) * 3125 + (blockIdx.x >> 3);
    const int e0   = tile * 64 + w * 16;           // this wave's 16 edges
    unsigned int* B1  = lds + w * 1088;            // 16 rows x 68 words
    unsigned int* MID = B1;                        // aliased; stride 36

    // ea fragment (k=128..135) for quad0; zeros for quads 1-3 (k=136..159)
    union { uint4 u; bf16x8 b; } eacv;
    eacv.u = ea_pk[e0 + l15];
    const bf16x8 zfrag = {0, 0, 0, 0, 0, 0, 0, 0};
    const bf16x8 ks4frag = (quad == 0) ? eacv.b : zfrag;

    // stage h2 rows: 32 half-rows (edge x {dst,src}) x 8 uint4; 4 iters b128
#pragma unroll
    for (int i = 0; i < 4; ++i) {
        int hr   = i * 8 + (lane >> 3);            // half-row 0..31
        int p    = e0 + (hr >> 1);
        int node = (hr & 1) ? ssrc[p] : sdst[p];
        int w4   = (lane & 7) * 4;
        uint4 v = *(const uint4*)(h2 + (size_t)node * 32 + w4);
        *(uint4*)(B1 + (hr >> 1) * 68 + (hr & 1) * 32 + w4) = v;
    }

    // GEMM1: C1^T[ch][edge], K=160 (ks 0..3 from LDS, ks=4 from registers)
    f32x4 acc1[4] = {{0,0,0,0},{0,0,0,0},{0,0,0,0},{0,0,0,0}};
    const unsigned int* brow = B1 + l15 * 68;
    for (int ks = 0; ks < 4; ++ks) {
        bf16x8 bfrag = *(const bf16x8*)(brow + ks * 16 + quad * 4);
        const short* apk = W1pk + (size_t)(ks * 4) * 512 + lane * 8;
#pragma unroll
        for (int mt = 0; mt < 4; ++mt) {
            bf16x8 afrag = *(const bf16x8*)(apk + mt * 512);
            acc1[mt] = __builtin_amdgcn_mfma_f32_16x16x32_bf16(
                afrag, bfrag, acc1[mt], 0, 0, 0);
        }
    }
    {
        const short* apk = W1pk + (size_t)(4 * 4) * 512 + lane * 8;
#pragma unroll
        for (int mt = 0; mt < 4; ++mt) {
            bf16x8 afrag = *(const bf16x8*)(apk + mt * 512);
            acc1[mt] = __builtin_amdgcn_mfma_f32_16x16x32_bf16(
                afrag, ks4frag, acc1[mt], 0, 0, 0);
        }
    }
    // epilogue 1: bias + silu -> MID (aliased over B1; all B1 reads complete)
#pragma unroll
    for (int mt = 0; mt < 4; ++mt) {
        int ch0 = mt * 16 + quad * 4;
        float v0 = silu_f(acc1[mt][0] + b1[ch0 + 0]);
        float v1 = silu_f(acc1[mt][1] + b1[ch0 + 1]);
        float v2 = silu_f(acc1[mt][2] + b1[ch0 + 2]);
        float v3 = silu_f(acc1[mt][3] + b1[ch0 + 3]);
        uint2 pk;
        pk.x = pack_bf16x2(v0, v1);
        pk.y = pack_bf16x2(v2, v3);
        *(uint2*)(MID + l15 * 36 + mt * 8 + quad * 2) = pk;
    }

    // GEMM2: C2^T[ch][edge], K=64 (2 ks)
    f32x4 acc2[4] = {{0,0,0,0},{0,0,0,0},{0,0,0,0},{0,0,0,0}};
    const unsigned int* mrow = MID + l15 * 36;
    for (int ks = 0; ks < 2; ++ks) {
        bf16x8 bfrag = *(const bf16x8*)(mrow + ks * 16 + quad * 4);
        const short* apk = W2pk + (size_t)(ks * 4) * 512 + lane * 8;
#pragma unroll
        for (int mt = 0; mt < 4; ++mt) {
            bf16x8 afrag = *(const bf16x8*)(apk + mt * 512);
            acc2[mt] = __builtin_amdgcn_mfma_f32_16x16x32_bf16(
                afrag, bfrag, acc2[mt], 0, 0, 0);
        }
    }

    // bias + LN over the 64 channels of this lane's edge
    float vals[16];
    float s1 = 0.f, s2 = 0.f;
#pragma unroll
    for (int mt = 0; mt < 4; ++mt) {
#pragma unroll
        for (int r = 0; r < 4; ++r) {
            int ch = mt * 16 + quad * 4 + r;
            float vv = acc2[mt][r] + b2[ch];
            vals[mt * 4 + r] = vv;
            s1 += vv; s2 += vv * vv;
        }
    }
    s1 += __shfl_xor(s1, 16); s1 += __shfl_xor(s1, 32);
    s2 += __shfl_xor(s2, 16); s2 += __shfl_xor(s2, 32);
    float mean = s1 * (1.0f / 64.0f);
    float var  = s2 * (1.0f / 64.0f) - mean * mean;
    float rstd = rsqrtf(var + 1e-5f);
#pragma unroll
    for (int mt = 0; mt < 4; ++mt) {
#pragma unroll
        for (int r = 0; r < 4; ++r) {
            int ch = mt * 16 + quad * 4 + r;
            vals[mt * 4 + r] = (vals[mt * 4 + r] - mean) * rstd * g[ch] + be[ch];
        }
    }

    // segmented inclusive scan over the wave's 16 edges (l15 dimension),
    // DPP row_shr; merge via fmaf with one mask per step.
    int d_l = sdst[e0 + l15];
#define SEG_STEP(CTRL)                                                        \
    {                                                                         \
        int d_up = dpp_i<CTRL>(-1, d_l);                                      \
        float msk = (d_up == d_l) ? 1.0f : 0.0f;                              \
        _Pragma("unroll")                                                     \
        for (int c = 0; c < 16; ++c) {                                        \
            float vu = __int_as_float(dpp_i<CTRL>(0, __float_as_int(vals[c])));\
            vals[c] = fmaf(vu, msk, vals[c]);                                 \
        }                                                                     \
    }
    SEG_STEP(0x111)   // row_shr:1
    SEG_STEP(0x112)   // row_shr:2
    SEG_STEP(0x114)   // row_shr:4
    SEG_STEP(0x118)   // row_shr:8
#undef SEG_STEP
    int d_next = dpp_i<0x101>(-1, d_l);   // row_shl:1 -> lane i gets i+1; lane15 -> -1
    bool last = (d_next != d_l);
    if (last) {
#pragma unroll
        for (int mt = 0; mt < 4; ++mt) {
#pragma unroll
            for (int r = 0; r < 4; ++r) {
                int ch = mt * 16 + quad * 4 + r;
                atomicAdd(&agg[(size_t)d_l * 64 + ch], vals[mt * 4 + r]);
            }
        }
    }
}

// ---------------------------------------------------------------------------
// Node MLP via MFMA + residual: h = h + LN(silu([h,agg]@W1+b1)@W2+b2)
// uint4/float4 staging; no __syncthreads. Updates h and h2.
// ---------------------------------------------------------------------------
__global__ __launch_bounds__(256, 6) void node_kernel(
    float* __restrict__ h, unsigned int* __restrict__ h2,
    const float* __restrict__ agg,
    const short* __restrict__ W1pk, const float* __restrict__ b1,
    const short* __restrict__ W2pk, const float* __restrict__ b2,
    const float* __restrict__ g, const float* __restrict__ be)
{
    __shared__ unsigned int lds[4 * 1088];
    const int lane = threadIdx.x & 63;
    const int w    = threadIdx.x >> 6;
    const int quad = lane >> 4;
    const int l15  = lane & 15;
    const int n0   = blockIdx.x * 64 + w * 16;     // this wave's 16 nodes
    unsigned int* B1  = lds + w * 1088;            // 16 rows x 68 words
    unsigned int* MID = B1;                        // aliased; stride 36

    // stage h2 rows (words 0..31): 16 rows x 8 uint4; 2 iters
#pragma unroll
    for (int i = 0; i < 2; ++i) {
        int row = i * 8 + (lane >> 3);
        int n = n0 + row; if (n >= NN) n = NN - 1;
        int w4 = (lane & 7) * 4;
        uint4 v = *(const uint4*)(h2 + (size_t)n * 32 + w4);
        *(uint4*)(B1 + row * 68 + w4) = v;
    }
    // stage agg (fp32 -> bf16, words 32..63): 16 rows x 16 float4; 4 iters
#pragma unroll
    for (int i = 0; i < 4; ++i) {
        int row = i * 4 + (lane >> 4);
        int n = n0 + row; if (n >= NN) n = NN - 1;
        int f4 = lane & 15;
        float4 v = *(const float4*)(agg + (size_t)n * 64 + f4 * 4);
        uint2 pk;
        pk.x = pack_bf16x2(v.x, v.y);
        pk.y = pack_bf16x2(v.z, v.w);
        *(uint2*)(B1 + row * 68 + 32 + f4 * 2) = pk;
    }

    // GEMM1: K=128 (4 ks)
    f32x4 acc1[4] = {{0,0,0,0},{0,0,0,0},{0,0,0,0},{0,0,0,0}};
    const unsigned int* brow = B1 + l15 * 68;
    for (int ks = 0; ks < 4; ++ks) {
        bf16x8 bfrag = *(const bf16x8*)(brow + ks * 16 + quad * 4);
        const short* apk = W1pk + (size_t)(ks * 4) * 512 + lane * 8;
#pragma unroll
        for (int mt = 0; mt < 4; ++mt) {
            bf16x8 afrag = *(const bf16x8*)(apk + mt * 512);
            acc1[mt] = __builtin_amdgcn_mfma_f32_16x16x32_bf16(
                afrag, bfrag, acc1[mt], 0, 0, 0);
        }
    }
#pragma unroll
    for (int mt = 0; mt < 4; ++mt) {
        int ch0 = mt * 16 + quad * 4;
        float v0 = silu_f(acc1[mt][0] + b1[ch0 + 0]);
        float v1 = silu_f(acc1[mt][1] + b1[ch0 + 1]);
        float v2 = silu_f(acc1[mt][2] + b1[ch0 + 2]);
        float v3 = silu_f(acc1[mt][3] + b1[ch0 + 3]);
        uint2 pk;
        pk.x = pack_bf16x2(v0, v1);
        pk.y = pack_bf16x2(v2, v3);
        *(uint2*)(MID + l15 * 36 + mt * 8 + quad * 2) = pk;
    }

    // GEMM2: K=64 (2 ks)
    f32x4 acc2[4] = {{0,0,0,0},{0,0,0,0},{0,0,0,0},{0,0,0,0}};
    const unsigned int* mrow = MID + l15 * 36;
    for (int ks = 0; ks < 2; ++ks) {
        bf16x8 bfrag = *(const bf16x8*)(mrow + ks * 16 + quad * 4);
        const short* apk = W2pk + (size_t)(ks * 4) * 512 + lane * 8;
#pragma unroll
        for (int mt = 0; mt < 4; ++mt) {
            bf16x8 afrag = *(const bf16x8*)(apk + mt * 512);
            acc2[mt] = __builtin_amdgcn_mfma_f32_16x16x32_bf16(
                afrag, bfrag, acc2[mt], 0, 0, 0);
        }
    }

    // bias + LN over the 64 channels of this lane's node
    float vals[16];
    float s1 = 0.f, s2 = 0.f;
#pragma unroll
    for (int mt = 0; mt < 4; ++mt) {
#pragma unroll
        for (int r = 0; r < 4; ++r) {
            int ch = mt * 16 + quad * 4 + r;
            float vv = acc2[mt][r] + b2[ch];
            vals[mt * 4 + r] = vv;
            s1 += vv; s2 += vv * vv;
        }
    }
    s1 += __shfl_xor(s1, 16); s1 += __shfl_xor(s1, 32);
    s2 += __shfl_xor(s2, 16); s2 += __shfl_xor(s2, 32);
    float mean = s1 * (1.0f / 64.0f);
    float var  = s2 * (1.0f / 64.0f) - mean * mean;
    float rstd = rsqrtf(var + 1e-5f);

    int n = n0 + l15;
    if (n < NN) {
#pragma unroll
        for (int mt = 0; mt < 4; ++mt) {
            int ch0 = mt * 16 + quad * 4;
            float4 hv = *(const float4*)(h + (size_t)n * 64 + ch0);
            float o0 = hv.x + (vals[mt*4+0] - mean) * rstd * g[ch0+0] + be[ch0+0];
            float o1 = hv.y + (vals[mt*4+1] - mean) * rstd * g[ch0+1] + be[ch0+1];
            float o2 = hv.z + (vals[mt*4+2] - mean) * rstd * g[ch0+2] + be[ch0+2];
            float o3 = hv.w + (vals[mt*4+3] - mean) * rstd * g[ch0+3] + be[ch0+3];
            float4 st = {o0, o1, o2, o3};
            *(float4*)(h + (size_t)n * 64 + ch0) = st;
            uint2 pk;
            pk.x = pack_bf16x2(o0, o1);
            pk.y = pack_bf16x2(o2, o3);
            *(uint2*)(h2 + (size_t)n * 32 + mt * 8 + quad * 2) = pk;
        }
    }
}

// ---------------------------------------------------------------------------
// Local decoder via MFMA: out_local = silu(h @ W1 + b1) @ W2 + b2 -> [NN, 6]
// ---------------------------------------------------------------------------
__global__ __launch_bounds__(256, 7) void dec_local_kernel(
    const unsigned int* __restrict__ h2,
    const short* __restrict__ W1pk, const float* __restrict__ b1,
    const short* __restrict__ W2pk, const float* __restrict__ b2,
    float* __restrict__ out)
{
    __shared__ unsigned int lds[4 * 576];
    const int lane = threadIdx.x & 63;
    const int w    = threadIdx.x >> 6;
    const int quad = lane >> 4;
    const int l15  = lane & 15;
    const int n0   = blockIdx.x * 64 + w * 16;
    unsigned int* B1  = lds + w * 576;             // 16 rows x 36 words
    unsigned int* MID = B1;                        // aliased; stride 36

    // stage h2: 16 rows x 8 uint4; 2 iters
#pragma unroll
    for (int i = 0; i < 2; ++i) {
        int row = i * 8 + (lane >> 3);
        int n = n0 + row; if (n >= NN) n = NN - 1;
        int w4 = (lane & 7) * 4;
        uint4 v = *(const uint4*)(h2 + (size_t)n * 32 + w4);
        *(uint4*)(B1 + row * 36 + w4) = v;
    }

    // GEMM1: K=64 (2 ks), M=64 (4 mt)
    f32x4 acc1[4] = {{0,0,0,0},{0,0,0,0},{0,0,0,0},{0,0,0,0}};
    const unsigned int* brow = B1 + l15 * 36;
    for (int ks = 0; ks < 2; ++ks) {
        bf16x8 bfrag = *(const bf16x8*)(brow + ks * 16 + quad * 4);
        const short* apk = W1pk + (size_t)(ks * 4) * 512 + lane * 8;
#pragma unroll
        for (int mt = 0; mt < 4; ++mt) {
            bf16x8 afrag = *(const bf16x8*)(apk + mt * 512);
            acc1[mt] = __builtin_amdgcn_mfma_f32_16x16x32_bf16(
                afrag, bfrag, acc1[mt], 0, 0, 0);
        }
    }
    // epilogue: bias + silu -> MID (bf16)
#pragma unroll
    for (int mt = 0; mt < 4; ++mt) {
        int ch0 = mt * 16 + quad * 4;
        float v0 = silu_f(acc1[mt][0] + b1[ch0 + 0]);
        float v1 = silu_f(acc1[mt][1] + b1[ch0 + 1]);
        float v2 = silu_f(acc1[mt][2] + b1[ch0 + 2]);
        float v3 = silu_f(acc1[mt][3] + b1[ch0 + 3]);
        uint2 pk;
        pk.x = pack_bf16x2(v0, v1);
        pk.y = pack_bf16x2(v2, v3);
        *(uint2*)(MID + l15 * 36 + mt * 8 + quad * 2) = pk;
    }

    // GEMM2: K=64 (2 ks), M=16 (out padded 6->16)
    f32x4 acc2 = {0, 0, 0, 0};
    const unsigned int* mrow = MID + l15 * 36;
    for (int ks = 0; ks < 2; ++ks) {
        bf16x8 bfrag = *(const bf16x8*)(mrow + ks * 16 + quad * 4);
        bf16x8 afrag = *(const bf16x8*)(W2pk + (size_t)ks * 512 + lane * 8);
        acc2 = __builtin_amdgcn_mfma_f32_16x16x32_bf16(afrag, bfrag, acc2, 0, 0, 0);
    }

    int n = n0 + l15;
    if (n < NN && quad < 2) {
#pragma unroll
        for (int r = 0; r < 4; ++r) {
            int ch = quad * 4 + r;
            if (ch < 6) out[(size_t)n * 6 + ch] = acc2[r] + b2[ch];
        }
    }
}

// ---------------------------------------------------------------------------
// Pooling: pooled[g][c] = sum_{batch[n]==g} h[n][c];  cnt[g] = count
// ---------------------------------------------------------------------------
__global__ __launch_bounds__(256) void pool_kernel(
    const float* __restrict__ h, const int* __restrict__ batch,
    float* __restrict__ pooled, float* __restrict__ cnt)
{
    const int c   = threadIdx.x & 63;
    const int rep = blockIdx.x * 4 + (threadIdx.x >> 6);   // 1024 reps
    float acc[NG] = {0.f, 0.f, 0.f, 0.f};
    float cl[NG]  = {0.f, 0.f, 0.f, 0.f};
    for (int n = rep; n < NN; n += 1024) {
        int b = batch[n];
        float v = h[n * 64 + c];
#pragma unroll
        for (int gph = 0; gph < NG; ++gph) {
            if (b == gph) { acc[gph] += v; cl[gph] += 1.0f; }
        }
    }
#pragma unroll
    for (int gph = 0; gph < NG; ++gph) {
        atomicAdd(&pooled[gph * 64 + c], acc[gph]);
        if (c == 0) atomicAdd(&cnt[gph], cl[gph]);
    }
}

// ---------------------------------------------------------------------------
// Global decoder: out_global = silu(mean_pool @ W1 + b1) @ W2 + b2 -> [4,4]
// ---------------------------------------------------------------------------
__global__ __launch_bounds__(256) void dec_global_kernel(
    const float* __restrict__ pooled, const float* __restrict__ cnt,
    const float* __restrict__ W1, const float* __restrict__ b1,
    const float* __restrict__ W2, const float* __restrict__ b2,
    float* __restrict__ out)
{
    __shared__ float mid_sh[4][32];
    const int lane = threadIdx.x & 63;
    const int gph  = threadIdx.x >> 6;
    float inv = 1.0f / fmaxf(cnt[gph], 1.0f);
    if (lane < 32) {
        float a = b1[lane];
        for (int k = 0; k < 64; ++k)
            a = fmaf(pooled[gph * 64 + k] * inv, W1[k * 32 + lane], a);
        mid_sh[gph][lane] = silu_f(a);
    }
    __syncthreads();
    if (lane < 4) {
        float o = b2[lane];
        for (int k = 0; k < 32; ++k)
            o = fmaf(mid_sh[gph][k], W2[k * 4 + lane], o);
        out[gph * 4 + lane] = o;
    }
}

// ---------------------------------------------------------------------------
extern "C" void kernel_launch(void* const* d_in, const int* in_sizes, int n_in,
                              void* d_out, int out_size, void* d_ws, size_t ws_size,
                              hipStream_t stream)
{
    const float* x      = (const float*)d_in[0];
    const int*   ei     = (const int*)  d_in[1];
    const float* ea     = (const float*)d_in[2];
    const int*   batch  = (const int*)  d_in[3];
    const float* case_p = (const float*)d_in[4];
    const float* bc_p   = (const float*)d_in[5];
    const float* enc_W1 = (const float*)d_in[6];
    const float* enc_b1 = (const float*)d_in[7];
    const float* enc_W2 = (const float*)d_in[8];
    const float* enc_b2 = (const float*)d_in[9];
    const float* enc_g  = (const float*)d_in[10];
    const float* enc_be = (const float*)d_in[11];
    const float* eW1    = (const float*)d_in[12];
    const float* eb1    = (const float*)d_in[13];
    const float* eW2    = (const float*)d_in[14];
    const float* eb2    = (const float*)d_in[15];
    const float* eg     = (const float*)d_in[16];
    const float* ebe    = (const float*)d_in[17];
    const float* nW1    = (const float*)d_in[18];
    const float* nb1    = (const float*)d_in[19];
    const float* nW2    = (const float*)d_in[20];
    const float* nb2    = (const float*)d_in[21];
    const float* ng     = (const float*)d_in[22];
    const float* nbe    = (const float*)d_in[23];
    const float* dlW1   = (const float*)d_in[24];
    const float* dlb1   = (const float*)d_in[25];
    const float* dlW2   = (const float*)d_in[26];
    const float* dlb2   = (const float*)d_in[27];
    const float* dgW1   = (const float*)d_in[28];
    const float* dgb1   = (const float*)d_in[29];
    const float* dgW2   = (const float*)d_in[30];
    const float* dgb2   = (const float*)d_in[31];

    float* out = (float*)d_out;

    char* ws = (char*)d_ws;
    size_t off_b = 0;
    auto alloc = [&](size_t bytes) {
        void* p = ws + off_b;
        off_b = (off_b + bytes + 255) & ~(size_t)255;
        return p;
    };
    const size_t hBytes = (size_t)NN * H * sizeof(float);     // 12.8 MB
    float*        h      = (float*)alloc(hBytes);
    float*        agg    = (float*)alloc(hBytes);
    unsigned int* h2     = (unsigned int*)alloc((size_t)NN * 32 * 4);  // bf16 mirror
    float*        pooled = (float*)alloc(256 * sizeof(float));
    float*        cnt    = (float*)alloc(4 * sizeof(float));
    int*          deg    = (int*)alloc((NN + 1) * sizeof(int));
    int*          offs   = (int*)alloc((NN + 1) * sizeof(int));
    int*          cursor = (int*)alloc((NN + 1) * sizeof(int));
    int*          bsum   = (int*)alloc(64 * sizeof(int));
    int*          bbase  = (int*)alloc(64 * sizeof(int));
    int*          sidx   = (int*)alloc((size_t)NE * sizeof(int));
    int*          sdst   = (int*)alloc((size_t)NE * sizeof(int));
    int*          ssrc   = (int*)alloc((size_t)NE * sizeof(int));
    uint4*        ea_pk  = (uint4*)alloc((size_t)NE * sizeof(uint4));  // 25.6 MB
    short*        eW1pk  = (short*)alloc((size_t)NL * 10240 * sizeof(short));
    short*        eW2pk  = (short*)alloc((size_t)NL * 4096 * sizeof(short));
    short*        nW1pk  = (short*)alloc((size_t)NL * 8192 * sizeof(short));
    short*        nW2pk  = (short*)alloc((size_t)NL * 4096 * sizeof(short));
    short*        dlW1pk = (short*)alloc(4096 * sizeof(short));
    short*        dlW2pk = (short*)alloc(1024 * sizeof(short));

    hipMemsetAsync(pooled, 0, (256 + 4 + 64) * sizeof(float), stream);
    hipMemsetAsync(deg, 0, (NN + 1) * sizeof(int), stream);

    const int NB = (NN + 1023) / 1024;   // 49
    degree_kernel<<<(NE + 255) / 256, 256, 0, stream>>>(ei, deg);
    scan1_kernel<<<NB, 1024, 0, stream>>>(deg, offs, bsum);
    scan2_kernel<<<1, 64, 0, stream>>>(bsum, bbase, NB);
    scan3_kernel<<<NB, 1024, 0, stream>>>(offs, bbase, cursor);
    scatter_kernel<<<(NE + 255) / 256, 256, 0, stream>>>(ei, cursor, sidx, sdst, ssrc);
    ea_pack_kernel<<<(NE + 255) / 256, 256, 0, stream>>>(ea, sidx, ea_pk);
    pack_weights_kernel<<<dim3(124, NL), 256, 0, stream>>>(
        eW1, eW2, nW1, nW2, dlW1, dlW2,
        eW1pk, eW2pk, nW1pk, nW2pk, dlW1pk, dlW2pk);

    const int nodeBlocks = (NN + 63) / 64;    // 782
    encoder_kernel<<<nodeBlocks, 256, 0, stream>>>(
        x, batch, case_p, bc_p, enc_W1, enc_b1, enc_W2, enc_b2, enc_g, enc_be,
        h, h2);

    for (int l = 0; l < NL; ++l) {
        hipMemsetAsync(agg, 0, hBytes, stream);
        edge_kernel<<<NE / 64, 256, 0, stream>>>(
            h2, sdst, ssrc, ea_pk,
            eW1pk + (size_t)l * 10240, eb1 + l * H,
            eW2pk + (size_t)l * 4096,  eb2 + l * H,
            eg + l * H, ebe + l * H, agg);
        node_kernel<<<nodeBlocks, 256, 0, stream>>>(
            h, h2, agg,
            nW1pk + (size_t)l * 8192, nb1 + l * H,
            nW2pk + (size_t)l * 4096, nb2 + l * H,
            ng + l * H, nbe + l * H);
    }

    dec_local_kernel<<<nodeBlocks, 256, 0, stream>>>(
        h2, dlW1pk, dlb1, dlW2pk, dlb2, out);
    pool_kernel<<<256, 256, 0, stream>>>(h, batch, pooled, cnt);
    dec_global_kernel<<<1, 256, 0, stream>>>(pooled, cnt, dgW1, dgb1, dgW2, dgb2,
                                             out + (size_t)NN * 6);
}